// Round 1
// baseline (2415.629 us; speedup 1.0000x reference)
//
#include <hip/hip_runtime.h>
#include <hip/hip_bf16.h>
#include <math.h>

#define T_TOK 4096
#define H_DIM 2048
#define I_DIM 8192
#define N_EXP 8
#define NPAIR 8192   // T_TOK * top_k

typedef short bf16x8 __attribute__((ext_vector_type(8)));
typedef float f32x4 __attribute__((ext_vector_type(4)));

__device__ __forceinline__ ushort f2bf(float f) {
    union { float f; unsigned u; } v; v.f = f;
    unsigned u = v.u + 0x7fffu + ((v.u >> 16) & 1u);  // RNE
    return (ushort)(u >> 16);
}

// ---------------- init: out = bias, zero counters ----------------
__global__ void k_init(float* __restrict__ out, const float* __restrict__ bias,
                       int* __restrict__ cnts) {
    int gid = blockIdx.x * 256 + threadIdx.x;
    size_t i = (size_t)gid * 4;
    if (i < (size_t)T_TOK * H_DIM) {
        float4 b = *(const float4*)&bias[i & (H_DIM - 1)];
        *(float4*)&out[i] = b;
    }
    if (gid < 16) cnts[gid] = 0;
}

// ---------------- x -> bf16 ----------------
__global__ void k_cvt_x(const float* __restrict__ x, ushort* __restrict__ xb) {
    size_t i = ((size_t)blockIdx.x * 256 + threadIdx.x) * 4;
    float4 v = *(const float4*)&x[i];
    ushort4 o;
    o.x = f2bf(v.x); o.y = f2bf(v.y); o.z = f2bf(v.z); o.w = f2bf(v.w);
    *(ushort4*)&xb[i] = o;
}

// ---------------- router: logits, top-2, weights, histogram ----------------
__global__ void k_router(const float* __restrict__ x, const float* __restrict__ gw,
                         float* __restrict__ logits, int* __restrict__ sel,
                         float* __restrict__ wts, int* __restrict__ cnt) {
    int t = blockIdx.x;
    int lane = threadIdx.x;
    const float* xr = x + (size_t)t * H_DIM;
    float s[8] = {0, 0, 0, 0, 0, 0, 0, 0};
    for (int h = lane; h < H_DIM; h += 64) {
        float xv = xr[h];
        const float* g = gw + h * 8;
        float4 g0 = *(const float4*)g;
        float4 g1 = *(const float4*)(g + 4);
        s[0] += xv * g0.x; s[1] += xv * g0.y; s[2] += xv * g0.z; s[3] += xv * g0.w;
        s[4] += xv * g1.x; s[5] += xv * g1.y; s[6] += xv * g1.z; s[7] += xv * g1.w;
    }
#pragma unroll
    for (int off = 32; off > 0; off >>= 1) {
#pragma unroll
        for (int e = 0; e < 8; e++) s[e] += __shfl_xor(s[e], off);
    }
    if (lane < 8) logits[t * 8 + lane] = s[lane];
    if (lane == 0) {
        int e0 = 0; float l0 = s[0];
        for (int e = 1; e < 8; e++) if (s[e] > l0) { l0 = s[e]; e0 = e; }
        int e1 = -1; float l1 = -3.0e38f;
        for (int e = 0; e < 8; e++) if (e != e0 && s[e] > l1) { l1 = s[e]; e1 = e; }
        float w0 = 1.0f / (1.0f + expf(l1 - l0));  // softmax over {l0,l1}
        float w1 = 1.0f - w0;
        sel[t * 2] = e0; sel[t * 2 + 1] = e1;
        wts[t * 2] = w0; wts[t * 2 + 1] = w1;
        atomicAdd(&cnt[e0], 1);
        atomicAdd(&cnt[e1], 1);
    }
}

// ---------------- prefix sum over 8 counts ----------------
__global__ void k_prefix(const int* __restrict__ cnt, int* __restrict__ offs) {
    if (threadIdx.x == 0 && blockIdx.x == 0) {
        int a = 0;
        for (int e = 0; e < N_EXP; e++) { offs[e] = a; a += cnt[e]; }
        offs[N_EXP] = a;
    }
}

// ---------------- assign pair -> row ----------------
__global__ void k_assign(const int* __restrict__ sel, const float* __restrict__ wts,
                         const int* __restrict__ offs, int* __restrict__ cursor,
                         int* __restrict__ rowinfo, float* __restrict__ rowwt) {
    int t = blockIdx.x * 256 + threadIdx.x;
    if (t >= T_TOK) return;
#pragma unroll
    for (int k = 0; k < 2; k++) {
        int e = sel[t * 2 + k];
        int pos = atomicAdd(&cursor[e], 1);
        int row = offs[e] + pos;
        rowinfo[row] = t;
        rowwt[row] = wts[t * 2 + k];
    }
}

// ---------------- MFMA GEMM: 128x128 tile, bf16 16x16x32 ----------------
// MODE 0: A = xb gathered via rowinfo, epilogue gelu -> hmid bf16
// MODE 1: A = hmid direct rows, epilogue *rowwt -> atomicAdd out
template <int KDIM, int NDIM, int MODE>
__global__ __launch_bounds__(256) void k_gemm(
    const ushort* __restrict__ Abase, const float* __restrict__ Bbase,
    void* __restrict__ outp, const int* __restrict__ rowinfo,
    const float* __restrict__ rowwt, const int* __restrict__ offs) {
    const int e = blockIdx.z;
    const int row_start = offs[e], row_end = offs[e + 1];
    const int row0 = row_start + blockIdx.y * 128;
    if (row0 >= row_end) return;
    const int n0 = blockIdx.x * 128;
    const float* B = Bbase + (size_t)e * KDIM * NDIM;

    __shared__ ushort lds_a[128 * 56];
    __shared__ ushort lds_b[128 * 56];

    const int tid = threadIdx.x;
    // A staging: thread -> (row, k-half)
    const int ar = tid & 127;
    const int ak = (tid >> 7) << 4;  // 0 or 16
    int r = row0 + ar;
    int rc = (r < row_end) ? r : row_start;  // clamp padding rows to a valid row
    const ushort* a_src;
    if (MODE == 0) a_src = Abase + (size_t)rowinfo[rc] * KDIM + ak;
    else           a_src = Abase + (size_t)rc * KDIM + ak;
    ushort* a_dst = &lds_a[ar * 56 + ak];

    // B staging: thread -> (4 n-cols, 4 k-rows); transpose to [n][k] in LDS
    const int bn = (tid & 31) * 4;
    const int bk = (tid >> 5) * 4;
    const float* b_src = B + (size_t)bk * NDIM + (n0 + bn);

    const int lane = tid & 63;
    const int wid = tid >> 6;
    const int wm = (wid & 1) * 64;
    const int wn = (wid >> 1) * 64;
    const int l15 = lane & 15;
    const int q8 = (lane >> 4) * 8;

    f32x4 acc[4][4] = {};

    for (int k0 = 0; k0 < KDIM; k0 += 32) {
        uint4 av0 = *(const uint4*)(a_src + k0);
        uint4 av1 = *(const uint4*)(a_src + k0 + 8);
        const float* bs = b_src + (size_t)k0 * NDIM;
        float4 b0 = *(const float4*)(bs);
        float4 b1 = *(const float4*)(bs + NDIM);
        float4 b2 = *(const float4*)(bs + 2 * (size_t)NDIM);
        float4 b3 = *(const float4*)(bs + 3 * (size_t)NDIM);
        __syncthreads();
        *(uint4*)a_dst = av0;
        *(uint4*)(a_dst + 8) = av1;
        {
            ushort4 p;
            p.x = f2bf(b0.x); p.y = f2bf(b1.x); p.z = f2bf(b2.x); p.w = f2bf(b3.x);
            *(ushort4*)&lds_b[(bn + 0) * 56 + bk] = p;
            p.x = f2bf(b0.y); p.y = f2bf(b1.y); p.z = f2bf(b2.y); p.w = f2bf(b3.y);
            *(ushort4*)&lds_b[(bn + 1) * 56 + bk] = p;
            p.x = f2bf(b0.z); p.y = f2bf(b1.z); p.z = f2bf(b2.z); p.w = f2bf(b3.z);
            *(ushort4*)&lds_b[(bn + 2) * 56 + bk] = p;
            p.x = f2bf(b0.w); p.y = f2bf(b1.w); p.z = f2bf(b2.w); p.w = f2bf(b3.w);
            *(ushort4*)&lds_b[(bn + 3) * 56 + bk] = p;
        }
        __syncthreads();
        bf16x8 af[4], bfr[4];
#pragma unroll
        for (int mt = 0; mt < 4; mt++)
            af[mt] = *(const bf16x8*)&lds_a[(wm + mt * 16 + l15) * 56 + q8];
#pragma unroll
        for (int nt = 0; nt < 4; nt++)
            bfr[nt] = *(const bf16x8*)&lds_b[(wn + nt * 16 + l15) * 56 + q8];
#pragma unroll
        for (int mt = 0; mt < 4; mt++)
#pragma unroll
            for (int nt = 0; nt < 4; nt++)
                acc[mt][nt] = __builtin_amdgcn_mfma_f32_16x16x32_bf16(
                    af[mt], bfr[nt], acc[mt][nt], 0, 0, 0);
    }

    const int qr = (lane >> 4) * 4;
#pragma unroll
    for (int mt = 0; mt < 4; mt++) {
#pragma unroll
        for (int rg = 0; rg < 4; rg++) {
            int rl = wm + mt * 16 + qr + rg;
            int rglob = row0 + rl;
            if (rglob < row_end) {
                if (MODE == 0) {
                    ushort* hm = (ushort*)outp + (size_t)rglob * NDIM + n0 + wn + l15;
#pragma unroll
                    for (int nt = 0; nt < 4; nt++) {
                        float v = acc[mt][nt][rg];
                        v = 0.5f * v * (1.0f + erff(v * 0.70710678118654752f));
                        hm[nt * 16] = f2bf(v);
                    }
                } else {
                    float w = rowwt[rglob];
                    int tok = rowinfo[rglob];
                    float* op = (float*)outp + (size_t)tok * NDIM + n0 + wn + l15;
#pragma unroll
                    for (int nt = 0; nt < 4; nt++)
                        atomicAdd(&op[nt * 16], w * acc[mt][nt][rg]);
                }
            }
        }
    }
}

// ---------------- launch ----------------
extern "C" void kernel_launch(void* const* d_in, const int* in_sizes, int n_in,
                              void* d_out, int out_size, void* d_ws, size_t ws_size,
                              hipStream_t stream) {
    const float* x     = (const float*)d_in[0];
    const float* gw    = (const float*)d_in[1];
    const float* w_in  = (const float*)d_in[2];
    const float* w_out = (const float*)d_in[3];
    const float* bias  = (const float*)d_in[4];

    float* out    = (float*)d_out;                       // [T*H]
    float* logits = out + (size_t)T_TOK * H_DIM;         // [T*8]

    char* ws = (char*)d_ws;
    ushort* xb      = (ushort*)(ws);                              // 16,777,216 B
    ushort* hmid    = (ushort*)(ws + 16777216);                   // 134,217,728 B
    int*    rowinfo = (int*)  (ws + 150994944);                   // 32 KB
    float*  rowwt   = (float*)(ws + 151027712);                   // 32 KB
    int*    sel     = (int*)  (ws + 151060480);                   // 32 KB
    float*  wts     = (float*)(ws + 151093248);                   // 32 KB
    int*    cnt     = (int*)  (ws + 151126016);                   // [16] counts+cursors
    int*    offs    = (int*)  (ws + 151126016 + 64);              // [9]

    hipLaunchKernelGGL(k_init,   dim3(8192), dim3(256), 0, stream, out, bias, cnt);
    hipLaunchKernelGGL(k_cvt_x,  dim3(8192), dim3(256), 0, stream, x, xb);
    hipLaunchKernelGGL(k_router, dim3(4096), dim3(64),  0, stream, x, gw, logits, sel, wts, cnt);
    hipLaunchKernelGGL(k_prefix, dim3(1),    dim3(64),  0, stream, cnt, offs);
    hipLaunchKernelGGL(k_assign, dim3(16),   dim3(256), 0, stream, sel, wts, offs, cnt + 8, rowinfo, rowwt);

    hipLaunchKernelGGL((k_gemm<H_DIM, I_DIM, 0>), dim3(64, 32, 8), dim3(256), 0, stream,
                       xb, w_in, (void*)hmid, rowinfo, rowwt, offs);
    hipLaunchKernelGGL((k_gemm<I_DIM, H_DIM, 1>), dim3(16, 32, 8), dim3(256), 0, stream,
                       hmid, w_out, (void*)out, rowinfo, rowwt, offs);
}